// Round 1
// 108.032 us; speedup vs baseline: 1.0310x; 1.0310x over previous
//
#include <hip/hip_runtime.h>

#define BATCH 4
#define NPTS  2048
#define DZDIM 128
#define GD    128
#define M_TOT (GD*GD)
#define TN    32
#define PZ    40        // Z LDS row pitch (ushorts); 20-dword stride -> worst 2-way banks (free)
#define ZP    2112      // zt / xs / wy row pitch (elements); 2048 data + 64 pad, 16B-aligned rows
#define WBIN  15        // +-15 bins: covers |x-gx| < 15.5*step (w < 7e-6 outside)

typedef __attribute__((ext_vector_type(8))) __bf16 bf16x8;
typedef __attribute__((ext_vector_type(4))) float floatx4;

__device__ __forceinline__ unsigned int f2bf_bits(float x){
  unsigned int u = __float_as_uint(x);
  u += 0x7FFFu + ((u >> 16) & 1u);
  return u >> 16;
}
__device__ __forceinline__ int point_bin(float px){
  int bin = __float2int_rn((px + 2.0f) * (127.0f / 4.0f));
  return min(GD - 1, max(0, bin));
}

// ---- fused: per-batch hist + scan + atomic-rank scatter (blocks 0..3) | x_grid bcast ----
// Order within a bin is arbitrary (atomic rank) — sums are order-independent; xs/perm stay
// consistent since both derive from the same j.
__global__ __launch_bounds__(256) void prep_kernel(
    const float* __restrict__ x, const float* __restrict__ grid,
    float* __restrict__ out, int* __restrict__ binStart,
    float2* __restrict__ xs, int* __restrict__ perm)
{
  const int tid = threadIdx.x;
  if (blockIdx.x < BATCH){
    __shared__ int h[GD];
    __shared__ int s[GD + 1];
    const int b = blockIdx.x;
    const float2* __restrict__ x2 = (const float2*)x;
    if (tid < GD) h[tid] = 0;
    __syncthreads();
    float2 xv[8]; int bn[8];
#pragma unroll
    for (int u = 0; u < 8; ++u){
      xv[u] = x2[b*NPTS + u*256 + tid];
      bn[u] = point_bin(xv[u].x);
      atomicAdd(&h[bn[u]], 1);
    }
    __syncthreads();
    if (tid == 0){
      int acc = 0;
#pragma unroll
      for (int j = 0; j < GD; ++j){ s[j] = acc; acc += h[j]; }
      s[GD] = acc;
    }
    __syncthreads();
    if (tid <= GD) binStart[b*(GD+1) + tid] = s[tid];
    if (tid < GD) h[tid] = 0;          // reuse as per-bin rank counters
    __syncthreads();
#pragma unroll
    for (int u = 0; u < 8; ++u){
      int j = s[bn[u]] + atomicAdd(&h[bn[u]], 1);
      xs[(long)b*ZP + j]       = xv[u];
      perm[b*NPTS + j]         = u*256 + tid;
    }
  } else {
    int idx = (blockIdx.x - BATCH) * 256 + tid;   // 0..32767 == GD*GD*2
    float g = grid[idx];
#pragma unroll
    for (int bb = 0; bb < BATCH; ++bb) out[bb*(GD*GD*2) + idx] = g;
  }
}

// ---- fused: zt[b][dz][j] = bf16(z[b][perm[j]][dz])  AND  wy[b][gy][j] = exp2(c1*dy^2) f32 ----
// wy is i-independent: 1M exps total instead of 32.8M inside the main kernel.
// Blocks x >= NPTS/32 zero-fill the wy pad columns [2048,2112) (NaN-safety for af=wy*0).
__global__ __launch_bounds__(256) void ztwy_kernel(
    const float* __restrict__ z, const float2* __restrict__ xs,
    const int* __restrict__ perm, const float* __restrict__ lsp,
    unsigned short* __restrict__ zt, float* __restrict__ wy)
{
  const int b   = blockIdx.y;
  const int jj  = threadIdx.x & 31;
  const int oct = threadIdx.x >> 5;          // 0..7
  if (blockIdx.x >= NPTS/32){
    int j = NPTS + (blockIdx.x - NPTS/32)*32 + jj;
#pragma unroll
    for (int yy = 0; yy < 16; ++yy)
      wy[(long)(b*GD + oct*16 + yy)*ZP + j] = 0.f;
    return;
  }
  const int j = blockIdx.x*32 + jj;
  const int n = perm[b*NPTS + j];
  const float4* __restrict__ z4 = (const float4*)z;
  const long rb = (long)(b*NPTS + n) * 32;
#pragma unroll
  for (int r = 0; r < 4; ++r){
    int c = oct*4 + r;                       // float4 index 0..31 -> dz = 4c..4c+3
    float4 v = z4[rb + c];
    long o = ((long)(b*DZDIM + 4*c) * ZP) + j;
    zt[o        ] = (unsigned short)f2bf_bits(v.x);
    zt[o +   ZP ] = (unsigned short)f2bf_bits(v.y);
    zt[o + 2*ZP ] = (unsigned short)f2bf_bits(v.z);
    zt[o + 3*ZP ] = (unsigned short)f2bf_bits(v.w);
  }
  const float l1 = 1e-5f + log1pf(expf(lsp[1]));
  const float c1 = -0.5f * 1.4426950408889634f / (l1*l1);
  const float step = 4.0f / 127.0f;
  const float y = xs[(long)b*ZP + j].y;
  float gy = -2.0f + (float)(oct*16) * step;
#pragma unroll
  for (int yy = 0; yy < 16; ++yy){
    float d = gy - y;
    wy[(long)(b*GD + oct*16 + yy)*ZP + j] = __builtin_amdgcn_exp2f(c1*d*d);
    gy += step;
  }
}

// ---- main: A-frag = cvt_pk(wy(global,f32) * wx(LDS bcast)); Wlds eliminated ----
__global__ __launch_bounds__(256, 4) void setconv_mfma_kernel(
    const float2* __restrict__ xs, const int* __restrict__ binStart,
    const unsigned short* __restrict__ zt, const float* __restrict__ wy,
    const float* __restrict__ lsp, float* __restrict__ outz)
{
  __shared__ __align__(16) unsigned short Zlds[2][DZDIM * PZ];  // 2 x 10240 B
  __shared__ __align__(16) float Wx[2][TN];                     // 2 x 128 B

  const int tid = threadIdx.x, lane = tid & 63, wv = tid >> 6;
  const int bid = blockIdx.x;
  const int g   = bid & 7;                   // XCD pin -> 16-row band (L2 locality)
  const int s   = bid >> 3;
  const int h   = s & 1;
  const int b   = (s >> 1) & 3;
  const int il  = s >> 3;                    // 0..15
  const int i   = g*16 + il;                 // grid row (gx index)
  const int my0 = h * 64;

  const float l0 = 1e-5f + log1pf(expf(lsp[0]));
  const float c0 = -0.5f * 1.4426950408889634f / (l0*l0);
  const float step = 4.0f / 127.0f;
  const float gx   = -2.0f + (float)i * step;

  const int lo  = binStart[b*(GD+1) + max(0, i - WBIN)];
  const int hi  = binStart[b*(GD+1) + min(GD-1, i + WBIN) + 1];
  const int lo8 = lo & ~7;                   // 16B-align k-base (extra pts get true tiny w)
  const int len = hi - lo8;
  const int T   = (len + TN - 1) / TN;

  // Z glds per-lane setup: 10 wave-instrs cover 128 rows x 5 chunks (4 data + 1 pad) of 16B
  int goff[3];
#pragma unroll
  for (int u = 0; u < 3; ++u){
    int gi = wv + 4*u;
    if (gi < 10){
      int pos = gi*64 + lane;
      int d = pos / 5, c = pos % 5;
      if (c > 3) c = 3;                      // pad chunk: duplicate a valid address
      goff[u] = (b*DZDIM + d) * ZP + c*8;
    } else goff[u] = 0;
  }

  const int q  = lane >> 4;
  const int ml = lane & 15;
  const float* __restrict__ wyp = wy + (long)(b*GD + my0 + wv*16 + ml) * ZP + q*8;

  floatx4 acc[8];
#pragma unroll
  for (int tz = 0; tz < 8; ++tz) acc[tz] = (floatx4){0.f, 0.f, 0.f, 0.f};

  auto stageZ = [&](int buf, int t){
    const int k0 = lo8 + t*TN;
#pragma unroll
    for (int u = 0; u < 3; ++u){
      int gi = wv + 4*u;
      if (gi < 10){
        const unsigned short* gp = zt + goff[u] + k0;
        __builtin_amdgcn_global_load_lds(
            (__attribute__((address_space(1))) void*)gp,
            (__attribute__((address_space(3))) void*)&Zlds[buf][gi*512],
            16, 0, 0);
      }
    }
  };
  auto stageWx = [&](int buf, int t){
    if (tid < TN){
      int ka = t*TN + tid;
      float2 xv = xs[(long)b*ZP + lo8 + ka];
      float d = gx - xv.x;
      float w = __builtin_amdgcn_exp2f(c0*d*d);
      Wx[buf][tid] = (ka < len) ? w : 0.f;
    }
  };

  if (T > 0){
    stageZ(0, 0);
    stageWx(0, 0);
    floatx4 wyA = *(const floatx4*)(wyp + lo8);
    floatx4 wyB = *(const floatx4*)(wyp + lo8 + 4);
    __syncthreads();
    for (int t = 0; t < T; ++t){
      const int cur = t & 1, nxt = 1 - cur;
      if (t + 1 < T){ stageZ(nxt, t + 1); stageWx(nxt, t + 1); }
      const int tp = (t + 1 < T) ? t + 1 : t;          // clamp: last prefetch unused
      floatx4 nA = *(const floatx4*)(wyp + lo8 + tp*TN);
      floatx4 nB = *(const floatx4*)(wyp + lo8 + tp*TN + 4);
      // A-frag: wy (regs, f32) * wx (LDS broadcast, uniform per 16-lane quarter)
      floatx4 wx0 = *(const floatx4*)&Wx[cur][q*8];
      floatx4 wx1 = *(const floatx4*)&Wx[cur][q*8 + 4];
      float p0 = wyA[0]*wx0[0], p1 = wyA[1]*wx0[1], p2 = wyA[2]*wx0[2], p3 = wyA[3]*wx0[3];
      float p4 = wyB[0]*wx1[0], p5 = wyB[1]*wx1[1], p6 = wyB[2]*wx1[2], p7 = wyB[3]*wx1[3];
      union { unsigned int u[4]; bf16x8 v; } A;
      asm("v_cvt_pk_bf16_f32 %0, %1, %2" : "=v"(A.u[0]) : "v"(p0), "v"(p1));
      asm("v_cvt_pk_bf16_f32 %0, %1, %2" : "=v"(A.u[1]) : "v"(p2), "v"(p3));
      asm("v_cvt_pk_bf16_f32 %0, %1, %2" : "=v"(A.u[2]) : "v"(p4), "v"(p5));
      asm("v_cvt_pk_bf16_f32 %0, %1, %2" : "=v"(A.u[3]) : "v"(p6), "v"(p7));
      bf16x8 af = A.v;
#pragma unroll
      for (int tz = 0; tz < 8; ++tz){
        bf16x8 bf = *(const bf16x8*)&Zlds[cur][(tz*16 + ml)*PZ + q*8];
        acc[tz] = __builtin_amdgcn_mfma_f32_16x16x32_bf16(af, bf, acc[tz], 0, 0, 0);
      }
      __syncthreads();                     // drains vmcnt (Z glds + wy prefetch)
      wyA = nA; wyB = nB;
    }
  }

  // epilogue: C/D col(dz)=ml, row(m)=q*4+r
  const long obase = ((long)(b*M_TOT + i*GD + my0 + wv*16 + q*4) << 7) + ml;
#pragma unroll
  for (int tz = 0; tz < 8; ++tz)
#pragma unroll
    for (int r = 0; r < 4; ++r)
      outz[obase + ((long)r << 7) + tz*16] = acc[tz][r];
}

extern "C" void kernel_launch(void* const* d_in, const int* in_sizes, int n_in,
                              void* d_out, int out_size, void* d_ws, size_t ws_size,
                              hipStream_t stream)
{
  const float* x    = (const float*)d_in[0];
  const float* z    = (const float*)d_in[1];
  const float* grid = (const float*)d_in[2];
  const float* lsp  = (const float*)d_in[3];
  float* out = (float*)d_out;

  char* ws = (char*)d_ws;
  int*            binStart = (int*)ws;                        // 4*129*4    = 2064 B
  int*            perm     = (int*)(ws + 2064);               // 4*2048*4   = 32768 B
  float2*         xs       = (float2*)(ws + 34832);           // 4*ZP*8     = 67584 B
  unsigned short* zt       = (unsigned short*)(ws + 102416);  // 4*128*ZP*2 = 2162688 B
  float*          wy       = (float*)(ws + 2265104);          // 4*128*ZP*4 = 4325376 B

  hipLaunchKernelGGL(prep_kernel, dim3(BATCH + GD), dim3(256), 0, stream,
                     x, grid, out, binStart, xs, perm);
  hipLaunchKernelGGL(ztwy_kernel, dim3(NPTS/32 + 2, BATCH), dim3(256), 0, stream,
                     z, xs, perm, lsp, zt, wy);
  hipLaunchKernelGGL(setconv_mfma_kernel, dim3(GD*2*BATCH), dim3(256), 0, stream,
                     xs, binStart, zt, wy, lsp, out + BATCH*GD*GD*2);
}